// Round 7
// baseline (100.027 us; speedup 1.0000x reference)
//
#include <hip/hip_runtime.h>

// Problem constants (fixed by reference setup_inputs()).
#define BB 8
#define CC 256
#define EE 18000
#define TT 4500
#define BT (BB * TT)     // 36000
#define BE (BB * EE)     // 144000
#define W  18            // elements per scan window
#define SS 19            // padded stride (pads never referenced: p+p/18 != 18 mod 19)
#define NW 512           // windows per half
#define PW (NW * SS)     // 9728 floats = 38912 B -> 4 blocks/CU
#define SP 9000          // nominal CSR split position (group-aligned split >= SP)

// ---------------- setup ----------------------------------------------------

__global__ void zero_counts_kernel(int* __restrict__ counts) {
    int i = blockIdx.x * blockDim.x + threadIdx.x;
    if (i < BT) counts[i] = 0;
}

__global__ void count_kernel(const int* __restrict__ gid, int* __restrict__ counts) {
    int i = blockIdx.x * blockDim.x + threadIdx.x;
    if (i < BE) {
        int b = i / EE;
        atomicAdd(&counts[b * TT + gid[i]], 1);
    }
}

// one block per batch: exclusive scan of counts -> off32 (pristine per-batch
// starts) and cursor (scatter cursor, base b*EE).
__global__ __launch_bounds__(1024) void scan_kernel(const int* __restrict__ counts,
                                                    int* __restrict__ off32,
                                                    int* __restrict__ cursor) {
    __shared__ int part[1024];
    const int b = blockIdx.x;
    const int t = threadIdx.x;
    const int CHUNK = 5;                          // 1024*5 >= 4500
    int lo = t * CHUNK; if (lo > TT) lo = TT;
    int hi = lo + CHUNK; if (hi > TT) hi = TT;
    int s = 0;
    for (int i = lo; i < hi; ++i) s += counts[b * TT + i];
    part[t] = s;
    __syncthreads();
    for (int d = 1; d < 1024; d <<= 1) {
        int v = (t >= d) ? part[t - d] : 0;
        __syncthreads();
        part[t] += v;
        __syncthreads();
    }
    int run = part[t] - s;                        // per-batch exclusive prefix
    for (int i = lo; i < hi; ++i) {
        off32[b * TT + i]  = run;
        cursor[b * TT + i] = b * EE + run;
        run += counts[b * TT + i];
    }
}

// find group-aligned split: first group g with off[g] >= SP. Unique satisfier
// does a plain global store (no shared memory, no atomics).
__global__ __launch_bounds__(512) void split_kernel(const int* __restrict__ off32,
                                                    int2* __restrict__ split2) {
    const int b = blockIdx.x;
    for (int g = threadIdx.x; g < TT; g += 512) {
        int st = off32[b * TT + g];
        if (st >= SP && g > 0 && off32[b * TT + g - 1] < SP)
            split2[b] = make_int2(g, st);
    }
}

// per-group epilogue tables with +1 sentinel (0 means "prefix = 0"):
//   qa[g] = 1 + pad(local_end-1)   if count>0 else 0
//   qb[g] = 1 + pad(local_start-1) if local_start>0 else 0
__global__ void table_kernel(const int* __restrict__ counts,
                             const int* __restrict__ off32,
                             const int2* __restrict__ split2,
                             unsigned short* __restrict__ qa16,
                             unsigned short* __restrict__ qb16,
                             float* __restrict__ inv32) {
    int i = blockIdx.x * blockDim.x + threadIdx.x;
    if (i < BT) {
        int b = i / TT;
        int g = i - b * TT;
        int2 s2 = split2[b];
        int st  = off32[i];
        int cnt = counts[i];
        int ls  = st - ((g >= s2.x) ? s2.y : 0);  // local start within half
        int le  = ls + cnt;                       // local end
        qa16[i] = cnt ? (unsigned short)((le - 1) + (le - 1) / W + 1) : 0;
        qb16[i] = ls  ? (unsigned short)((ls - 1) + (ls - 1) / W + 1) : 0;
        inv32[i] = cnt ? 1.0f / (float)cnt : 0.0f;
    }
}

// atomic CSR scatter (R4-proven); emits padded local position | half bit.
// Group-aligned split => position-half == group-half.
__global__ void scatter_kernel(const int* __restrict__ gid,
                               int* __restrict__ cursor,
                               const int2* __restrict__ split2,
                               unsigned short* __restrict__ prank16) {
    int i = blockIdx.x * blockDim.x + threadIdx.x;
    if (i < BE) {
        int b  = i / EE;
        int p  = atomicAdd(&cursor[b * TT + gid[i]], 1) - b * EE;
        int sp = split2[b].y;
        int h  = (p >= sp) ? 1 : 0;
        int lp = p - (h ? sp : 0);
        prank16[i] = (unsigned short)((lp + lp / W) | (h << 15));
    }
}

// ---------------- main: two half-passes, scatter + scan + regular epilogue -
// One block per (b,c), 512 threads, 38944 B LDS -> 4 blocks/CU = 32 waves.
// Per half: zero vals; scatter own-half elements (coalesced fe float4 +
// prank ushort4; pass 2 re-read mostly L2); per-window sum; per-wave shfl
// scan + 8 wave totals; elementwise prefix write-back; coalesced epilogue
// out[g] = (P(qa)-P(qb)) * inv with P(0)=0 sentinel (no g-1 chains, no
// empty-group hazards). All LDS zeroed -> no garbage reasoning needed.

__global__ __launch_bounds__(512) void pool_kernel(const float* __restrict__ fe,
                                                   const unsigned short* __restrict__ prank16,
                                                   const unsigned short* __restrict__ qa16,
                                                   const unsigned short* __restrict__ qb16,
                                                   const float* __restrict__ inv32,
                                                   const int2* __restrict__ split2,
                                                   float* __restrict__ out) {
    __shared__ float vals[PW];                    // 38912 B
    __shared__ float wsum[8];                     //    32 B
    const int b   = blockIdx.x >> 8;              // CC == 256
    const int c   = blockIdx.x & 255;
    const int tid = threadIdx.x;
    const int wv  = tid >> 6;
    const int ln  = tid & 63;

    const float4*  fe4 = (const float4*)(fe + (size_t)(b * CC + c) * EE);
    const ushort4* rk4 = (const ushort4*)(prank16 + (size_t)b * EE);
    const unsigned short* qa = qa16 + b * TT;
    const unsigned short* qb = qb16 + b * TT;
    const float*          iv = inv32 + b * TT;
    float* outb = out + (size_t)(b * CC + c) * TT;
    const int gs = split2[b].x;

    for (int h = 0; h < 2; ++h) {
        const int hb = h << 15;

        // zero the value buffer
        for (int i = tid; i < PW; i += 512) vals[i] = 0.0f;
        __syncthreads();

        // scatter this half's elements into padded CSR order
#pragma unroll
        for (int i = 0; i < 9; ++i) {
            int idx = tid + (i << 9);
            if (idx < EE / 4) {
                float4  v = fe4[idx];
                ushort4 r = rk4[idx];
                if ((r.x & 0x8000) == hb) vals[r.x & 0x7fff] = v.x;
                if ((r.y & 0x8000) == hb) vals[r.y & 0x7fff] = v.y;
                if ((r.z & 0x8000) == hb) vals[r.z & 0x7fff] = v.z;
                if ((r.w & 0x8000) == hb) vals[r.w & 0x7fff] = v.w;
            }
        }
        __syncthreads();

        // window sum
        const int base = SS * tid;
        float sum = 0.0f;
#pragma unroll
        for (int k = 0; k < W; ++k) sum += vals[base + k];

        // per-wave inclusive shfl scan of window sums
        float sc = sum;
#pragma unroll
        for (int d = 1; d < 64; d <<= 1) {
            float o = __shfl_up(sc, d, 64);
            if (ln >= d) sc += o;
        }
        if (ln == 63) wsum[wv] = sc;              // wave total
        __syncthreads();

        // cross-wave exclusive offset + elementwise prefix write-back
        float cross = 0.0f;
#pragma unroll
        for (int j = 0; j < 8; ++j) {
            float tw = wsum[j];                   // broadcast read
            if (j < wv) cross += tw;
        }
        float run = cross + (sc - sum);           // exclusive prefix of this window
#pragma unroll
        for (int k = 0; k < W; ++k) { run += vals[base + k]; vals[base + k] = run; }
        __syncthreads();

        // epilogue: contiguous group range of this half, coalesced stores
        const int glo = h ? gs : 0;
        const int ghi = h ? TT : gs;
        for (int g = glo + tid; g < ghi; g += 512) {
            int a = qa[g], bq = qb[g];
            float Pa = a  ? vals[a - 1]  : 0.0f;
            float Pb = bq ? vals[bq - 1] : 0.0f;
            outb[g] = (Pa - Pb) * iv[g];
        }
        __syncthreads();                          // protect vals before next pass
    }
}

extern "C" void kernel_launch(void* const* d_in, const int* in_sizes, int n_in,
                              void* d_out, int out_size, void* d_ws, size_t ws_size,
                              hipStream_t stream) {
    const float* fe  = (const float*)d_in[0];
    const int*   gid = (const int*)d_in[1];
    float*       out = (float*)d_out;

    // ws: counts[BT] i32 | cursor[BT] i32 | off32[BT] i32 | inv32[BT] f32 |
    //     qa16[BT] u16 | qb16[BT] u16 | prank16[BE] u16 | split2[BB] int2
    int*            counts  = (int*)d_ws;
    int*            cursor  = counts + BT;
    int*            off32   = cursor + BT;
    float*          inv32   = (float*)(off32 + BT);
    unsigned short* qa16    = (unsigned short*)(inv32 + BT);
    unsigned short* qb16    = qa16 + BT;
    unsigned short* prank16 = qb16 + BT;
    int2*           split2  = (int2*)(prank16 + BE);

    zero_counts_kernel<<<(BT + 255) / 256, 256, 0, stream>>>(counts);
    count_kernel<<<(BE + 255) / 256, 256, 0, stream>>>(gid, counts);
    scan_kernel<<<BB, 1024, 0, stream>>>(counts, off32, cursor);
    split_kernel<<<BB, 512, 0, stream>>>(off32, split2);
    table_kernel<<<(BT + 255) / 256, 256, 0, stream>>>(counts, off32, split2, qa16, qb16, inv32);
    scatter_kernel<<<(BE + 255) / 256, 256, 0, stream>>>(gid, cursor, split2, prank16);
    pool_kernel<<<BB * CC, 512, 0, stream>>>(fe, prank16, qa16, qb16, inv32, split2, out);
}

// Round 8
// 65.879 us; speedup vs baseline: 1.5183x; 1.5183x over previous
//
#include <hip/hip_runtime.h>

// Problem constants (fixed by reference setup_inputs()).
#define BB 8
#define CC 256
#define EE 18000
#define TT 4500
#define BT (BB * TT)     // 36000
#define BE (BB * EE)     // 144000
#define W  18            // elements per scan window
#define SS 19            // padded stride (odd: strided access = 2 lanes/bank, free)
#define NT 1024          // threads per pool block (16 waves)
#define PW (NT * SS)     // 19456 floats = 77824 B -> 2 blocks/CU = 32 waves = 100%

// ---------------- setup ----------------------------------------------------

__global__ void zero_counts_kernel(int* __restrict__ counts) {
    int i = blockIdx.x * blockDim.x + threadIdx.x;
    if (i < BT) counts[i] = 0;
}

__global__ void count_kernel(const int* __restrict__ gid, int* __restrict__ counts) {
    int i = blockIdx.x * blockDim.x + threadIdx.x;
    if (i < BE) {
        int b = i / EE;
        atomicAdd(&counts[b * TT + gid[i]], 1);
    }
}

// one block per batch: exclusive scan of counts -> cursor (scatter cursor,
// base b*EE) and fused epilogue table tab[g] = {qa|qb<<16, bits(inv)}:
//   qa = 1+pad(end-1)   if count>0 else 0   (pad(x) = x + x/W)
//   qb = 1+pad(start-1) if start>0 else 0
__global__ __launch_bounds__(1024) void scan_kernel(const int* __restrict__ counts,
                                                    int* __restrict__ cursor,
                                                    uint2* __restrict__ tab) {
    __shared__ int part[1024];
    const int b = blockIdx.x;
    const int t = threadIdx.x;
    const int CHUNK = 5;                          // 1024*5 >= 4500
    int lo = t * CHUNK; if (lo > TT) lo = TT;
    int hi = lo + CHUNK; if (hi > TT) hi = TT;
    int s = 0;
    for (int i = lo; i < hi; ++i) s += counts[b * TT + i];
    part[t] = s;
    __syncthreads();
    for (int d = 1; d < 1024; d <<= 1) {
        int v = (t >= d) ? part[t - d] : 0;
        __syncthreads();
        part[t] += v;
        __syncthreads();
    }
    int run = part[t] - s;                        // per-batch exclusive prefix
    for (int i = lo; i < hi; ++i) {
        int cnt = counts[b * TT + i];
        cursor[b * TT + i] = b * EE + run;
        int en = run + cnt;
        unsigned int qa = cnt ? (unsigned int)((en - 1) + (en - 1) / W + 1) : 0u;
        unsigned int qb = run ? (unsigned int)((run - 1) + (run - 1) / W + 1) : 0u;
        float inv = cnt ? 1.0f / (float)cnt : 0.0f;
        tab[b * TT + i] = make_uint2(qa | (qb << 16), __float_as_uint(inv));
        run = en;
    }
}

// atomic CSR scatter: prank16[e] = padded CSR position of edge e in batch b
__global__ void scatter_kernel(const int* __restrict__ gid,
                               int* __restrict__ cursor,
                               unsigned short* __restrict__ prank16) {
    int i = blockIdx.x * blockDim.x + threadIdx.x;
    if (i < BE) {
        int b = i / EE;
        int p = atomicAdd(&cursor[b * TT + gid[i]], 1) - b * EE;
        prank16[i] = (unsigned short)(p + p / W);  // max 18998 < 32768
    }
}

// ---------------- main: scatter + block prefix-scan + regular epilogue -----
// One block per (b,c), 1024 threads, 77.9 KB LDS -> 2 blocks/CU = 32 waves
// (100% occupancy). No LDS zeroing: CSR is dense (every real slot written);
// pad slots and positions >= 19000 are never read. Phase A keeps the window
// in registers with 2 accumulators; phase C runs two independent 9-chains.
// Windows 1000..1023 read garbage but only pollute wsum[15] (never consumed)
// and positions >= 19000 (never read).

__global__ __launch_bounds__(1024, 8) void pool_kernel(const float* __restrict__ fe,
                                                       const unsigned short* __restrict__ prank16,
                                                       const uint2* __restrict__ tab,
                                                       float* __restrict__ out) {
    __shared__ float vals[PW];                    // 77824 B
    __shared__ float wsum[16];
    const int b   = blockIdx.x >> 8;              // CC == 256
    const int c   = blockIdx.x & 255;
    const int tid = threadIdx.x;
    const int wv  = tid >> 6;
    const int ln  = tid & 63;

    // scatter row into padded CSR order (coalesced float4 + ushort4)
    const float4*  fe4 = (const float4*)(fe + (size_t)(b * CC + c) * EE);
    const ushort4* rk4 = (const ushort4*)(prank16 + (size_t)b * EE);
#pragma unroll
    for (int i = 0; i < 5; ++i) {                 // 5*1024 = 5120 >= 4500
        int idx = tid + (i << 10);
        if (idx < EE / 4) {
            float4  v = fe4[idx];
            ushort4 r = rk4[idx];
            vals[r.x] = v.x;
            vals[r.y] = v.y;
            vals[r.z] = v.z;
            vals[r.w] = v.w;
        }
    }
    __syncthreads();

    // phase A: window -> registers, two accumulators
    const int base = SS * tid;
    float v[W];
    float s0 = 0.0f, s1 = 0.0f;
#pragma unroll
    for (int k = 0; k < 9; ++k)  { v[k] = vals[base + k]; s0 += v[k]; }
#pragma unroll
    for (int k = 9; k < 18; ++k) { v[k] = vals[base + k]; s1 += v[k]; }
    const float sum = s0 + s1;

    // per-wave inclusive shfl scan of window sums
    float sc = sum;
#pragma unroll
    for (int d = 1; d < 64; d <<= 1) {
        float o = __shfl_up(sc, d, 64);
        if (ln >= d) sc += o;
    }
    if (ln == 63) wsum[wv] = sc;                  // wave total
    __syncthreads();

    // cross-wave exclusive offset
    float cross = 0.0f;
#pragma unroll
    for (int j = 0; j < 16; ++j) {
        float tw = wsum[j];                       // broadcast read
        if (j < wv) cross += tw;
    }

    // phase C: two independent 9-chains seeded by sub-sums
    float run0 = cross + (sc - sum);              // exclusive prefix of window
    float run1 = run0 + s0;
#pragma unroll
    for (int k = 0; k < 9; ++k)  { run0 += v[k]; vals[base + k] = run0; }
#pragma unroll
    for (int k = 9; k < 18; ++k) { run1 += v[k]; vals[base + k] = run1; }
    __syncthreads();

    // epilogue: one 8B table load per group; coalesced stores
    const uint2* tb   = tab + b * TT;
    float*       outb = out + (size_t)(b * CC + c) * TT;
#pragma unroll
    for (int k = 0; k < 5; ++k) {                 // 5*1024 = 5120 >= 4500
        int g = tid + (k << 10);
        if (g < TT) {
            uint2 q = tb[g];
            unsigned int a  = q.x & 0xffffu;
            unsigned int bq = q.x >> 16;
            float Pa = a  ? vals[a - 1]  : 0.0f;
            float Pb = bq ? vals[bq - 1] : 0.0f;
            outb[g] = (Pa - Pb) * __uint_as_float(q.y);
        }
    }
}

extern "C" void kernel_launch(void* const* d_in, const int* in_sizes, int n_in,
                              void* d_out, int out_size, void* d_ws, size_t ws_size,
                              hipStream_t stream) {
    const float* fe  = (const float*)d_in[0];
    const int*   gid = (const int*)d_in[1];
    float*       out = (float*)d_out;

    // ws: counts[BT] i32 | cursor[BT] i32 | tab[BT] uint2 | prank16[BE] u16
    int*            counts  = (int*)d_ws;
    int*            cursor  = counts + BT;
    uint2*          tab     = (uint2*)(cursor + BT);          // offset 288000 B (8-aligned)
    unsigned short* prank16 = (unsigned short*)(tab + BT);

    zero_counts_kernel<<<(BT + 255) / 256, 256, 0, stream>>>(counts);
    count_kernel<<<(BE + 255) / 256, 256, 0, stream>>>(gid, counts);
    scan_kernel<<<BB, 1024, 0, stream>>>(counts, cursor, tab);
    scatter_kernel<<<(BE + 255) / 256, 256, 0, stream>>>(gid, cursor, prank16);
    pool_kernel<<<BB * CC, 1024, 0, stream>>>(fe, prank16, tab, out);
}